// Round 1
// baseline (455.535 us; speedup 1.0000x reference)
//
#include <hip/hip_runtime.h>
#include <cstdint>
#include <cstddef>

#define Bsz 8
#define Ssz 256
#define Tsz 128
#define Dsz 64
#define Psz 128
#define Msz (Bsz*Ssz)   // 2048
#define SPLITK 16

// ---------- transpose [128 rows x K cols] -> [K x 128] ----------
__global__ void k_transpose128(const float* __restrict__ in, float* __restrict__ out, int K) {
  __shared__ float tile[32][33];
  int kb = blockIdx.x * 32;
  int rb = blockIdx.y * 32;
  int x = threadIdx.x;                 // 0..31
  for (int yy = threadIdx.y; yy < 32; yy += 8)
    tile[yy][x] = in[(size_t)(rb + yy) * K + kb + x];
  __syncthreads();
  for (int yy = threadIdx.y; yy < 32; yy += 8)
    out[(size_t)(kb + yy) * 128 + rb + x] = tile[x][yy];
}

// ---------- fused outer-product GEMM with split-K ----------
// C_partial[sk][m][n] = sum_{k in chunk} (tok[m, k>>lgDv] * v[m, k&mask]) * Bm[k][n]
__global__ __launch_bounds__(256) void k_gemm(
    const float* __restrict__ tok,   // [Msz][128]
    const float* __restrict__ v,     // [Msz][1<<lgDv]
    const float* __restrict__ Bm,    // [K][128] k-major
    float* __restrict__ part,        // [SPLITK][Msz][128]
    int lgDv, int Kc)                // Kc = K / SPLITK
{
  __shared__ float As[2][16][132];   // [kk][m], padded stride 132 (16B aligned, bank-spread)
  __shared__ float Bs[2][16][128];   // [kk][n]
  const int tid = threadIdx.x;
  const int tx = tid & 15;           // n-group: n = tx*8 + j
  const int ty = tid >> 4;           // m-group: m = ty*8 + i
  const int m0 = blockIdx.x * 128;
  const int k0base = blockIdx.y * Kc;
  const int dmask = (1 << lgDv) - 1;

  float acc[8][8];
  #pragma unroll
  for (int i = 0; i < 8; i++)
    #pragma unroll
    for (int j = 0; j < 8; j++) acc[i][j] = 0.f;

  auto stage = [&](int buf, int ks) {
    const int k0 = k0base + ks * 16;
    const int t  = k0 >> lgDv;
    const int d0 = k0 & dmask;
    #pragma unroll
    for (int r = 0; r < 8; r++) {      // A tile: 16kk x 128m
      int e  = tid + 256 * r;
      int kk = e & 15, mm = e >> 4;
      As[buf][kk][mm] = tok[(size_t)(m0 + mm) * 128 + t]
                      * v[((size_t)(m0 + mm) << lgDv) + d0 + kk];
    }
    #pragma unroll
    for (int r = 0; r < 8; r++) {      // B tile: 16kk x 128n (coalesced)
      int e  = tid + 256 * r;
      int nn = e & 127, kk = e >> 7;
      Bs[buf][kk][nn] = Bm[(size_t)(k0 + kk) * 128 + nn];
    }
  };

  stage(0, 0);
  const int nb = Kc >> 4;
  for (int ks = 0; ks < nb; ks++) {
    __syncthreads();
    const int cur = ks & 1;
    if (ks + 1 < nb) stage(cur ^ 1, ks + 1);
    #pragma unroll
    for (int kk = 0; kk < 16; kk++) {
      float4 a0 = *reinterpret_cast<const float4*>(&As[cur][kk][ty * 8]);
      float4 a1 = *reinterpret_cast<const float4*>(&As[cur][kk][ty * 8 + 4]);
      float4 b0 = *reinterpret_cast<const float4*>(&Bs[cur][kk][tx * 8]);
      float4 b1 = *reinterpret_cast<const float4*>(&Bs[cur][kk][tx * 8 + 4]);
      float a[8] = {a0.x,a0.y,a0.z,a0.w,a1.x,a1.y,a1.z,a1.w};
      float b[8] = {b0.x,b0.y,b0.z,b0.w,b1.x,b1.y,b1.z,b1.w};
      #pragma unroll
      for (int i = 0; i < 8; i++)
        #pragma unroll
        for (int j = 0; j < 8; j++)
          acc[i][j] += a[i] * b[j];
    }
  }

  float* dst = part + ((size_t)blockIdx.y * Msz + m0) * 128;
  #pragma unroll
  for (int i = 0; i < 8; i++) {
    float4 c0 = make_float4(acc[i][0], acc[i][1], acc[i][2], acc[i][3]);
    float4 c1 = make_float4(acc[i][4], acc[i][5], acc[i][6], acc[i][7]);
    *reinterpret_cast<float4*>(&dst[(size_t)(ty * 8 + i) * 128 + tx * 8])     = c0;
    *reinterpret_cast<float4*>(&dst[(size_t)(ty * 8 + i) * 128 + tx * 8 + 4]) = c1;
  }
}

// ---------- split-K reduce + bias + tanh ----------
__global__ void k_reduce_tanh(const float* __restrict__ part, const float* __restrict__ bias,
                              float* __restrict__ out) {
  int e = blockIdx.x * 256 + threadIdx.x;   // total = Msz*128 = 262144
  float s = bias[e & 127];
  #pragma unroll
  for (int sk = 0; sk < SPLITK; sk++) s += part[(size_t)sk * (Msz * 128) + e];
  out[e] = tanhf(s);
}

// ---------- epilogue: gather over j with head[b,j]==i ----------
__global__ __launch_bounds__(128) void k_finalize(
    const float* __restrict__ special,  // [Msz][128]
    const int*   __restrict__ heads,    // [Bsz][Ssz]
    const float* __restrict__ wred,     // [Ssz]
    const float* __restrict__ bred,     // [1]
    const float* __restrict__ bcomp,    // [128]
    float* __restrict__ out)            // [Bsz][Ssz][128]
{
  int b = blockIdx.x >> 8;
  int i = blockIdx.x & 255;
  int t = threadIdx.x;
  __shared__ float wr_s[Ssz];
  __shared__ int   hd_s[Ssz];
  wr_s[t]        = wred[t];
  wr_s[t + 128]  = wred[t + 128];
  hd_s[t]        = heads[b * Ssz + t];
  hd_s[t + 128]  = heads[b * Ssz + t + 128];
  __syncthreads();

  float base = tanhf(bcomp[t]);
  float swr = 0.f, accv = 0.f;
  for (int j = 0; j < Ssz; j++) {
    swr += wr_s[j];
    if (hd_s[j] == i)   // block-uniform branch
      accv += wr_s[j] * (special[((size_t)b * Ssz + j) * 128 + t] - base);
  }
  out[((size_t)b * Ssz + i) * 128 + t] = base * swr + bred[0] + accv;
}

extern "C" void kernel_launch(void* const* d_in, const int* in_sizes, int n_in,
                              void* d_out, int out_size, void* d_ws, size_t ws_size,
                              hipStream_t stream) {
  const float* tok   = (const float*)d_in[0];
  const float* dep   = (const float*)d_in[1];
  const int*   hds   = (const int*)  d_in[2];
  const float* Wdep  = (const float*)d_in[3];
  const float* bdep  = (const float*)d_in[4];
  const float* Wcomp = (const float*)d_in[5];
  const float* bcomp = (const float*)d_in[6];
  const float* Wred  = (const float*)d_in[7];
  const float* bred  = (const float*)d_in[8];
  float* out = (float*)d_out;

  float* ws   = (float*)d_ws;
  float* W1T  = ws;                    // 8192*128    = 1,048,576 f
  float* W2T  = W1T + 1048576;         // 16384*128   = 2,097,152 f
  float* part = W2T + 2097152;         // 16*2048*128 = 4,194,304 f
  float* h    = part + 4194304;        // 262,144 f
  float* spc  = h + 262144;            // 262,144 f   (total ~30 MB)

  k_transpose128<<<dim3(8192 / 32, 4),  dim3(32, 8), 0, stream>>>(Wdep,  W1T, 8192);
  k_transpose128<<<dim3(16384 / 32, 4), dim3(32, 8), 0, stream>>>(Wcomp, W2T, 16384);

  // Phase 1: tde partials (K=8192, Dv=64)
  k_gemm<<<dim3(Msz / 128, SPLITK), 256, 0, stream>>>(tok, dep, W1T, part, 6, 8192 / SPLITK);
  k_reduce_tanh<<<(Msz * 128) / 256, 256, 0, stream>>>(part, bdep, h);

  // Phase 2: composition partials (K=16384, Dv=128)
  k_gemm<<<dim3(Msz / 128, SPLITK), 256, 0, stream>>>(tok, h, W2T, part, 7, 16384 / SPLITK);
  k_reduce_tanh<<<(Msz * 128) / 256, 256, 0, stream>>>(part, bcomp, spc);

  k_finalize<<<dim3(Bsz * Ssz), 128, 0, stream>>>(spc, hds, Wred, bred, bcomp, out);
}

// Round 2
// 73.004 us; speedup vs baseline: 6.2398x; 6.2398x over previous
//
#include <hip/hip_runtime.h>
#include <cstdint>
#include <cstddef>

#define Bsz 8
#define Ssz 256
#define Msz (Bsz*Ssz)   // 2048
#define SPLITK 16
#define BM 64
#define BN 128
#define BK 64

typedef _Float16 f16x8 __attribute__((ext_vector_type(8)));
typedef _Float16 f16x4 __attribute__((ext_vector_type(4)));
typedef float f32x4 __attribute__((ext_vector_type(4)));

// ---------- fp32 -> fp16 elementwise (W stays in native [n][k] layout) ----------
__global__ void k_cvt_f32_f16(const float* __restrict__ in, _Float16* __restrict__ out, int n4) {
  int i = blockIdx.x * 256 + threadIdx.x;
  if (i < n4) {
    float4 v = reinterpret_cast<const float4*>(in)[i];
    f16x4 o = { (_Float16)v.x, (_Float16)v.y, (_Float16)v.z, (_Float16)v.w };
    reinterpret_cast<f16x4*>(out)[i] = o;
  }
}

// ---------- MFMA GEMM: C_part[sk][m][n] += (tok[m,t]*v[m,d]) * Bw[n][k] over k-chunk ----------
// A[m,k] built on the fly in fp16 (k = t*Dv + d). Bw is [128][Ktot] fp16 row-major (= [n][k]).
__global__ __launch_bounds__(256) void k_gemm_mfma(
    const float* __restrict__ tok,      // [Msz][128] fp32
    const float* __restrict__ v,        // [Msz][1<<lgDv] fp32
    const _Float16* __restrict__ Bw,    // [128][Ktot] fp16
    float* __restrict__ part,           // [SPLITK][Msz][128] fp32
    int lgDv, int Kc, int Ktot)
{
  __shared__ __align__(16) _Float16 Al[2][BM * BK];   // phys byte = row*128 + (slot^(row&7))*16
  __shared__ __align__(16) _Float16 Bl[2][BN * BK];

  const int tid  = threadIdx.x;
  const int lane = tid & 63;
  const int wave = tid >> 6;
  const int wr = wave >> 1;            // m-half of block tile (0..1)
  const int wc = wave & 1;             // n-half (0..1)
  const int m0 = blockIdx.x * BM;
  const int k0base = blockIdx.y * Kc;
  const int dmask = (1 << lgDv) - 1;

  // staging assignments
  const int am = tid >> 2, aq = tid & 3;   // A: row am (0..63), 16 elems at d-local aq*16
  const int bn = tid >> 1, bh = tid & 1;   // B: row bn (0..127), 32 elems at k-local bh*32

  f32x4 acc[2][4];
  #pragma unroll
  for (int i = 0; i < 2; i++)
    #pragma unroll
    for (int j = 0; j < 4; j++) acc[i][j] = (f32x4){0.f, 0.f, 0.f, 0.f};

  float s_tv; float4 s_v0, s_v1, s_v2, s_v3;
  f16x8 s_b0, s_b1, s_b2, s_b3;

  auto load_stage = [&](int ks) {
    const int k0 = k0base + ks * BK;
    const int t  = k0 >> lgDv;
    const int d0 = k0 & dmask;
    s_tv = tok[(size_t)(m0 + am) * 128 + t];
    const float4* vp = reinterpret_cast<const float4*>(&v[((size_t)(m0 + am) << lgDv) + d0 + aq * 16]);
    s_v0 = vp[0]; s_v1 = vp[1]; s_v2 = vp[2]; s_v3 = vp[3];
    const f16x8* bp = reinterpret_cast<const f16x8*>(&Bw[(size_t)bn * Ktot + k0 + bh * 32]);
    s_b0 = bp[0]; s_b1 = bp[1]; s_b2 = bp[2]; s_b3 = bp[3];
  };

  auto write_stage = [&](int buf) {
    float va[16] = { s_v0.x, s_v0.y, s_v0.z, s_v0.w,  s_v1.x, s_v1.y, s_v1.z, s_v1.w,
                     s_v2.x, s_v2.y, s_v2.z, s_v2.w,  s_v3.x, s_v3.y, s_v3.z, s_v3.w };
    f16x8 pa, pb;
    #pragma unroll
    for (int i = 0; i < 8; i++) { pa[i] = (_Float16)(s_tv * va[i]); pb[i] = (_Float16)(s_tv * va[8 + i]); }
    char* Ab = (char*)&Al[buf][0];
    const int axor = am & 7;
    *reinterpret_cast<f16x8*>(Ab + am * 128 + ((2 * aq)     ^ axor) * 16) = pa;
    *reinterpret_cast<f16x8*>(Ab + am * 128 + ((2 * aq + 1) ^ axor) * 16) = pb;
    char* Bb = (char*)&Bl[buf][0];
    const int bxor = bn & 7;
    *reinterpret_cast<f16x8*>(Bb + bn * 128 + ((bh * 4 + 0) ^ bxor) * 16) = s_b0;
    *reinterpret_cast<f16x8*>(Bb + bn * 128 + ((bh * 4 + 1) ^ bxor) * 16) = s_b1;
    *reinterpret_cast<f16x8*>(Bb + bn * 128 + ((bh * 4 + 2) ^ bxor) * 16) = s_b2;
    *reinterpret_cast<f16x8*>(Bb + bn * 128 + ((bh * 4 + 3) ^ bxor) * 16) = s_b3;
  };

  // frag-read address pieces (swizzle XOR value reduces to lane&7 since 16|row offsets)
  const int l15 = lane & 15, lg = lane >> 4, lx = lane & 7;
  const int aBase = (wr * 32 + l15) * 128;
  const int bBase = (wc * 64 + l15) * 128;
  const int slot0 = ((0 * 4 + lg) ^ lx) * 16;   // k-half 0
  const int slot1 = ((1 * 4 + lg) ^ lx) * 16;   // k-half 1

  load_stage(0);
  write_stage(0);
  __syncthreads();

  const int nb = Kc / BK;
  int cur = 0;
  for (int s = 0; s < nb; ++s) {
    const bool more = (s + 1 < nb);
    if (more) load_stage(s + 1);          // issue global loads early; latency hides under MFMA

    const char* Ab = (const char*)&Al[cur][0];
    const char* Bb = (const char*)&Bl[cur][0];
    f16x8 af[2][2], bf[4][2];
    #pragma unroll
    for (int mf = 0; mf < 2; mf++) {
      af[mf][0] = *reinterpret_cast<const f16x8*>(Ab + aBase + mf * 2048 + slot0);
      af[mf][1] = *reinterpret_cast<const f16x8*>(Ab + aBase + mf * 2048 + slot1);
    }
    #pragma unroll
    for (int nf = 0; nf < 4; nf++) {
      bf[nf][0] = *reinterpret_cast<const f16x8*>(Bb + bBase + nf * 2048 + slot0);
      bf[nf][1] = *reinterpret_cast<const f16x8*>(Bb + bBase + nf * 2048 + slot1);
    }
    #pragma unroll
    for (int kh = 0; kh < 2; kh++)
      #pragma unroll
      for (int mf = 0; mf < 2; mf++)
        #pragma unroll
        for (int nf = 0; nf < 4; nf++)
          acc[mf][nf] = __builtin_amdgcn_mfma_f32_16x16x32_f16(af[mf][kh], bf[nf][kh], acc[mf][nf], 0, 0, 0);

    __syncthreads();                       // everyone done reading buf `cur`
    if (more) write_stage(cur ^ 1);        // products + LDS writes into the idle buffer
    __syncthreads();                       // stage visible before next reads
    cur ^= 1;
  }

  // C/D layout: col = lane&15, row = (lane>>4)*4 + r  (guide §3, m89-verified)
  float* dst = part + ((size_t)blockIdx.y * Msz + m0) * 128;
  #pragma unroll
  for (int mf = 0; mf < 2; mf++)
    #pragma unroll
    for (int nf = 0; nf < 4; nf++) {
      const int col = wc * 64 + nf * 16 + l15;
      #pragma unroll
      for (int r = 0; r < 4; r++) {
        const int row = wr * 32 + mf * 16 + lg * 4 + r;
        dst[(size_t)row * 128 + col] = acc[mf][nf][r];
      }
    }
}

// ---------- split-K reduce + bias + tanh ----------
__global__ void k_reduce_tanh(const float* __restrict__ part, const float* __restrict__ bias,
                              float* __restrict__ out) {
  int e = blockIdx.x * 256 + threadIdx.x;   // total = Msz*128 = 262144
  float s = bias[e & 127];
  #pragma unroll
  for (int sk = 0; sk < SPLITK; sk++) s += part[(size_t)sk * (Msz * 128) + e];
  out[e] = tanhf(s);
}

// ---------- epilogue: gather over j with head[b,j]==i ----------
__global__ __launch_bounds__(128) void k_finalize(
    const float* __restrict__ special,  // [Msz][128]
    const int*   __restrict__ heads,    // [Bsz][Ssz]
    const float* __restrict__ wred,     // [Ssz]
    const float* __restrict__ bred,     // [1]
    const float* __restrict__ bcomp,    // [128]
    float* __restrict__ out)            // [Bsz][Ssz][128]
{
  int b = blockIdx.x >> 8;
  int i = blockIdx.x & 255;
  int t = threadIdx.x;
  __shared__ float wr_s[Ssz];
  __shared__ int   hd_s[Ssz];
  wr_s[t]        = wred[t];
  wr_s[t + 128]  = wred[t + 128];
  hd_s[t]        = heads[b * Ssz + t];
  hd_s[t + 128]  = heads[b * Ssz + t + 128];
  __syncthreads();

  float base = tanhf(bcomp[t]);
  float swr = 0.f, accv = 0.f;
  for (int j = 0; j < Ssz; j++) {
    swr += wr_s[j];
    if (hd_s[j] == i)
      accv += wr_s[j] * (special[((size_t)b * Ssz + j) * 128 + t] - base);
  }
  out[((size_t)b * Ssz + i) * 128 + t] = base * swr + bred[0] + accv;
}

extern "C" void kernel_launch(void* const* d_in, const int* in_sizes, int n_in,
                              void* d_out, int out_size, void* d_ws, size_t ws_size,
                              hipStream_t stream) {
  const float* tok   = (const float*)d_in[0];
  const float* dep   = (const float*)d_in[1];
  const int*   hds   = (const int*)  d_in[2];
  const float* Wdep  = (const float*)d_in[3];
  const float* bdep  = (const float*)d_in[4];
  const float* Wcomp = (const float*)d_in[5];
  const float* bcomp = (const float*)d_in[6];
  const float* Wred  = (const float*)d_in[7];
  const float* bred  = (const float*)d_in[8];
  float* out = (float*)d_out;

  char* ws = (char*)d_ws;
  _Float16* W1h = (_Float16*)ws;                       //  2 MB (128*8192)
  _Float16* W2h = (_Float16*)(ws + (2u<<20));          //  4 MB (128*16384)
  float*    part= (float*)  (ws + (6u<<20));           // 16 MB (16*2048*128)
  float*    h   = (float*)  (ws + (22u<<20));          //  1 MB
  float*    spc = (float*)  (ws + (23u<<20));          //  1 MB

  k_cvt_f32_f16<<<1024, 256, 0, stream>>>(Wdep,  W1h, 1048576 / 4);
  k_cvt_f32_f16<<<2048, 256, 0, stream>>>(Wcomp, W2h, 2097152 / 4);

  // Phase 1: tde (M=2048, N=128, K=8192, Dv=64)
  k_gemm_mfma<<<dim3(Msz / BM, SPLITK), 256, 0, stream>>>(tok, dep, W1h, part, 6, 8192 / SPLITK, 8192);
  k_reduce_tanh<<<(Msz * 128) / 256, 256, 0, stream>>>(part, bdep, h);

  // Phase 2: composition (M=2048, N=128, K=16384, Dv=128)
  k_gemm_mfma<<<dim3(Msz / BM, SPLITK), 256, 0, stream>>>(tok, h, W2h, part, 7, 16384 / SPLITK, 16384);
  k_reduce_tanh<<<(Msz * 128) / 256, 256, 0, stream>>>(part, bcomp, spc);

  k_finalize<<<dim3(Bsz * Ssz), 128, 0, stream>>>(spc, hds, Wred, bred, bcomp, out);
}